// Round 2
// baseline (198.177 us; speedup 1.0000x reference)
//
#include <hip/hip_runtime.h>
#include <hip/hip_bf16.h>

// ---------------------------------------------------------------------------
// NaiveFourierKANLayer as GEMM:  y = [cos|sin features][4096 x 32768] * W + b
//   F[b, k] = trig_{k>>6}( x[b, i] * ((k&63)+1) )   (per-i chunks of 128)
//   W[k, o] = fouriercoeffs[k>>6][o][i][k&63]
// bf16 MFMA 16x16x32, 128x128 block tile, splitK=8 over i, atomic fp32 epilogue.
// LDS tiles stored in fragment-linear "image" layout -> conflict-free b128 ops.
// ---------------------------------------------------------------------------

typedef __attribute__((ext_vector_type(8))) short short8;
typedef __attribute__((ext_vector_type(4))) float f32x4;

#define SPLITK 8
#define ICHUNK (256 / SPLITK)   // 32 i's per block

// round-to-nearest-even f32 -> bf16, two packed into 32 bits
__device__ __forceinline__ unsigned short f2bf(float f) {
    unsigned u = __builtin_bit_cast(unsigned, f);
    u += 0x7fffu + ((u >> 16) & 1u);
    return (unsigned short)(u >> 16);
}
__device__ __forceinline__ unsigned pkbf16(float a, float b) {
    return (unsigned)f2bf(a) | ((unsigned)f2bf(b) << 16);
}

// out[b][o] = bias[o]  (1M floats as 256K float4)
__global__ void init_out_kernel(float* __restrict__ out, const float* __restrict__ bias) {
    int tid = blockIdx.x * 256 + threadIdx.x;          // 0..262143
    float4 b4 = ((const float4*)bias)[tid & 63];        // 256 cols / 4
    ((float4*)out)[tid] = b4;
}

// fouriercoeffs[t][o][i][g] (fp32) -> ws[i][o][t*64+g] (bf16)
// reads: 2KB contiguous per wave; writes: full 128B lines.
__global__ void convert_coeffs_kernel(const float* __restrict__ fc,
                                      unsigned short* __restrict__ ws) {
    unsigned tid = blockIdx.x * 256 + threadIdx.x;      // 2^20 threads
    int oct = tid & 7;
    int i   = (tid >> 3) & 255;
    int o   = (tid >> 11) & 255;
    int t   = tid >> 19;
    const float4* src = (const float4*)(fc + ((((size_t)t * 256 + o) * 256 + i) * 64 + oct * 8));
    float4 a = src[0], b = src[1];
    uint4 v;
    v.x = pkbf16(a.x, a.y); v.y = pkbf16(a.z, a.w);
    v.z = pkbf16(b.x, b.y); v.w = pkbf16(b.z, b.w);
    *(uint4*)(ws + (((size_t)i * 256 + o) * 128 + t * 64 + oct * 8)) = v;
}

// Image granule index for element (row-or-col r, k): (s*8 + r>>4)*64 + q*16 + (r&15)
// where s = k>>5, q = (k>>3)&3.  Frag read for (group og, kstep s): lane l reads
// granule (s*8+og)*64 + l  -> lane-consecutive 16B -> conflict-free.
template <bool USE_WS>
__global__ __launch_bounds__(256, 2) void fkan_gemm(
    const float* __restrict__ x, const float* __restrict__ fc,
    const unsigned short* __restrict__ bws, float* __restrict__ out)
{
    __shared__ uint4 Aimg[2048];   // 32 KB: features, 128 rows x 128 k
    __shared__ uint4 Bimg[2048];   // 32 KB: coeffs,   128 cols x 128 k

    const int t  = threadIdx.x;
    const int l  = t & 63;
    const int w  = t >> 6;
    const int wr = w >> 1, wc = w & 1;            // 2x2 waves of 64x64
    const int rowBase = blockIdx.x * 128;
    const int colBase = blockIdx.y * 128;
    const int iBase   = blockIdx.z * ICHUNK;
    const int fr = t & 127;                        // feature row
    const int tg = t >> 7;                         // 0=cos chain, 1=sin chain

    f32x4 acc[4][4];
    #pragma unroll
    for (int a = 0; a < 4; ++a)
        #pragma unroll
        for (int b = 0; b < 4; ++b) acc[a][b] = (f32x4)0.0f;

    const float* xrow = x + (size_t)(rowBase + fr) * 256;

    #pragma unroll 1
    for (int ii = 0; ii < ICHUNK; ++ii) {
        const int i = iBase + ii;

        // ---- stage A: Fourier features via Chebyshev step-2 recurrence ----
        float xv = xrow[i];
        float s1 = __sinf(xv);
        float c1 = __cosf(xv);
        float c2 = __builtin_fmaf(2.f * c1, c1, -1.f);   // cos 2x
        float s2 = 2.f * s1 * c1;                        // sin 2x
        float m2 = 2.f * c2;
        // pair (f(g_odd), f(g_even)) starting (g=1, g=2); prev = (g=-1, g=0)
        float cx, cy, px, py;
        if (tg == 0) { cx = c1; cy = c2; px = c1;  py = 1.f; }
        else         { cx = s1; cy = s2; px = -s1; py = 0.f; }
        {
            const int og = fr >> 4;
            const int lrow = fr & 15;
            #pragma unroll
            for (int oct = 0; oct < 8; ++oct) {
                unsigned pk0, pk1, pk2, pk3;
                pk0 = pkbf16(cx, cy);
                { float nx = __builtin_fmaf(m2, cx, -px), ny = __builtin_fmaf(m2, cy, -py);
                  px = cx; py = cy; cx = nx; cy = ny; }
                pk1 = pkbf16(cx, cy);
                { float nx = __builtin_fmaf(m2, cx, -px), ny = __builtin_fmaf(m2, cy, -py);
                  px = cx; py = cy; cx = nx; cy = ny; }
                pk2 = pkbf16(cx, cy);
                { float nx = __builtin_fmaf(m2, cx, -px), ny = __builtin_fmaf(m2, cy, -py);
                  px = cx; py = cy; cx = nx; cy = ny; }
                pk3 = pkbf16(cx, cy);
                { float nx = __builtin_fmaf(m2, cx, -px), ny = __builtin_fmaf(m2, cy, -py);
                  px = cx; py = cy; cx = nx; cy = ny; }
                int k = tg * 64 + oct * 8;
                int s = k >> 5;
                int q = (k >> 3) & 3;
                uint4 v; v.x = pk0; v.y = pk1; v.z = pk2; v.w = pk3;
                Aimg[(s * 8 + og) * 64 + q * 16 + lrow] = v;
            }
        }

        // ---- stage B: coeff tile, written directly in image order ----
        #pragma unroll
        for (int gg = 0; gg < 8; ++gg) {
            int gi  = gg * 256 + t;          // image granule index (write-linear)
            int sog = gi >> 6;
            int ll  = gi & 63;
            int s = sog >> 3, og = sog & 7;
            int o = og * 16 + (ll & 15);
            int k = s * 32 + (ll >> 4) * 8;
            uint4 v;
            if (USE_WS) {
                v = *(const uint4*)(bws + ((size_t)i * (256 * 128) +
                                           (size_t)(colBase + o) * 128 + k));
            } else {
                int tt = k >> 6, g = k & 63;
                const float4* p = (const float4*)(fc +
                    ((((size_t)tt * 256 + colBase + o) * 256 + i) * 64 + g));
                float4 a = p[0], b = p[1];
                v.x = pkbf16(a.x, a.y); v.y = pkbf16(a.z, a.w);
                v.z = pkbf16(b.x, b.y); v.w = pkbf16(b.z, b.w);
            }
            Bimg[gi] = v;
        }

        __syncthreads();

        // ---- MFMA: 4 ksteps x (4 row-frags x 4 col-frags) ----
        #pragma unroll
        for (int s = 0; s < 4; ++s) {
            short8 aF[4], bF[4];
            #pragma unroll
            for (int rf = 0; rf < 4; ++rf)
                aF[rf] = __builtin_bit_cast(short8, Aimg[(s * 8 + wr * 4 + rf) * 64 + l]);
            #pragma unroll
            for (int cf = 0; cf < 4; ++cf)
                bF[cf] = __builtin_bit_cast(short8, Bimg[(s * 8 + wc * 4 + cf) * 64 + l]);
            #pragma unroll
            for (int rf = 0; rf < 4; ++rf)
                #pragma unroll
                for (int cf = 0; cf < 4; ++cf)
                    acc[rf][cf] = __builtin_amdgcn_mfma_f32_16x16x32_bf16(
                        aF[rf], bF[cf], acc[rf][cf], 0, 0, 0);
        }

        __syncthreads();
    }

    // ---- epilogue: C/D layout col=l&15, row=(l>>4)*4+e ; splitK via atomics ----
    const int lr = (l >> 4) * 4;
    const int lc = l & 15;
    const int r0 = rowBase + wr * 64 + lr;
    const int c0 = colBase + wc * 64 + lc;
    #pragma unroll
    for (int rf = 0; rf < 4; ++rf)
        #pragma unroll
        for (int cf = 0; cf < 4; ++cf)
            #pragma unroll
            for (int e = 0; e < 4; ++e)
                atomicAdd(out + (size_t)(r0 + rf * 16 + e) * 256 + (c0 + cf * 16),
                          acc[rf][cf][e]);
}

extern "C" void kernel_launch(void* const* d_in, const int* in_sizes, int n_in,
                              void* d_out, int out_size, void* d_ws, size_t ws_size,
                              hipStream_t stream) {
    const float* x    = (const float*)d_in[0];
    const float* fc   = (const float*)d_in[1];
    const float* bias = (const float*)d_in[2];
    float* out = (float*)d_out;
    unsigned short* bws = (unsigned short*)d_ws;

    hipLaunchKernelGGL(init_out_kernel, dim3(1024), dim3(256), 0, stream, out, bias);

    const size_t wsNeed = (size_t)256 * 256 * 128 * sizeof(unsigned short);  // 16.78 MB
    if (ws_size >= wsNeed) {
        hipLaunchKernelGGL(convert_coeffs_kernel, dim3(4096), dim3(256), 0, stream, fc, bws);
        hipLaunchKernelGGL((fkan_gemm<true>), dim3(32, 2, SPLITK), dim3(256), 0, stream,
                           x, fc, bws, out);
    } else {
        hipLaunchKernelGGL((fkan_gemm<false>), dim3(32, 2, SPLITK), dim3(256), 0, stream,
                           x, fc, bws, out);
    }
}

// Round 3
// 179.685 us; speedup vs baseline: 1.1029x; 1.1029x over previous
//
#include <hip/hip_runtime.h>
#include <hip/hip_bf16.h>

// ---------------------------------------------------------------------------
// NaiveFourierKANLayer as GEMM:  y = [cos|sin features][4096 x 32768] * W + b
// bf16 MFMA 16x16x32, 128x128 tile, splitK=8, atomic fp32 epilogue.
// R3: ws2 holds coeffs pre-transposed into the LDS fragment-image granule
// order -> B staged with async global_load_lds (16B); A/B fragments are
// register-prefetched between the two barriers so MFMA overlaps next-iter
// feature VALU + async loads (m97-style K-loop).
// ---------------------------------------------------------------------------

typedef __attribute__((ext_vector_type(8))) short short8;
typedef __attribute__((ext_vector_type(4))) float f32x4;

#define SPLITK 8
#define ICHUNK (256 / SPLITK)   // 32 i's per block

// round-to-nearest-even f32 -> bf16
__device__ __forceinline__ unsigned short f2bf(float f) {
    unsigned u = __builtin_bit_cast(unsigned, f);
    u += 0x7fffu + ((u >> 16) & 1u);
    return (unsigned short)(u >> 16);
}
__device__ __forceinline__ unsigned pkbf16(float a, float b) {
    return (unsigned)f2bf(a) | ((unsigned)f2bf(b) << 16);
}

// async 16B global->LDS (dest = wave-uniform base + lane*16)
__device__ __forceinline__ void async_load16(const void* g, void* l) {
    __builtin_amdgcn_global_load_lds(
        (const __attribute__((address_space(1))) unsigned int*)g,
        (__attribute__((address_space(3))) unsigned int*)l,
        16, 0, 0);
}

// out[b][o] = bias[o]
__global__ void init_out_kernel(float* __restrict__ out, const float* __restrict__ bias) {
    int tid = blockIdx.x * 256 + threadIdx.x;          // 0..262143
    float4 b4 = ((const float4*)bias)[tid & 63];
    ((float4*)out)[tid] = b4;
}

// Image granule gi = (s*8+og)*64 + q*16 + lano :
//   col o' = og*16+lano (0..127), k = s*32+q*8 (+j, j=0..7), tt = k>>6, g = k&63
// ws2[(i*2+y)*2048 + gi] = bf16(fc[tt][y*128+o'][i][g..g+7])  -- 16B granules.
__global__ __launch_bounds__(256) void convert_coeffs2(
    const float* __restrict__ fc, unsigned short* __restrict__ ws2)
{
    __shared__ unsigned short lsh[256 * 72];   // strip-major, +8 pad (36 KB)
    const int bx = blockIdx.x;                 // 0..511 = i*2 + y
    const int i = bx >> 1, y = bx & 1;
    const int t = threadIdx.x;

    // phase 1: strip t = [tt|o'] reads its 64 fp32, packs to bf16 in LDS
    {
        const int tt = t >> 7, op = t & 127;
        const float4* src = (const float4*)(fc +
            ((((size_t)tt * 256) + y * 128 + op) * 256 + i) * 64);
        uint4* dst = (uint4*)(lsh + t * 72);
        #pragma unroll
        for (int q2 = 0; q2 < 8; ++q2) {
            float4 a = src[q2 * 2], b = src[q2 * 2 + 1];
            uint4 v;
            v.x = pkbf16(a.x, a.y); v.y = pkbf16(a.z, a.w);
            v.z = pkbf16(b.x, b.y); v.w = pkbf16(b.z, b.w);
            dst[q2] = v;
        }
    }
    __syncthreads();

    // phase 2: write granules image-linear (fully coalesced 16B stores)
    uint4* wdst = (uint4*)ws2 + (size_t)bx * 2048;
    #pragma unroll
    for (int rep = 0; rep < 8; ++rep) {
        int gi = rep * 256 + t;
        int sog = gi >> 6, ll = gi & 63;
        int s = sog >> 3, og = sog & 7;
        int op = og * 16 + (ll & 15);
        int k = s * 32 + ((ll >> 4) * 8);
        int tt = k >> 6, g0 = k & 63;
        wdst[gi] = *(const uint4*)(lsh + (tt * 128 + op) * 72 + g0);
    }
}

template <bool USE_WS>
__global__ __launch_bounds__(256, 2) void fkan_gemm(
    const float* __restrict__ x, const float* __restrict__ fc,
    const unsigned short* __restrict__ bws, float* __restrict__ out)
{
    __shared__ uint4 Aimg[2048];   // 32 KB: features image
    __shared__ uint4 Bimg[2048];   // 32 KB: coeff image

    const int t  = threadIdx.x;
    const int l  = t & 63;
    const int w  = t >> 6;
    const int wr = w >> 1, wc = w & 1;            // 2x2 waves of 64x64
    const int rowBase = blockIdx.x * 128;
    const int by      = blockIdx.y;
    const int colBase = by * 128;
    const int iBase   = blockIdx.z * ICHUNK;
    const int fr = t & 127;                        // feature row
    const int tg = t >> 7;                         // 0=cos chain, 1=sin chain

    f32x4 acc[4][4];
    #pragma unroll
    for (int a = 0; a < 4; ++a)
        #pragma unroll
        for (int b = 0; b < 4; ++b) acc[a][b] = (f32x4)0.0f;

    const float* xrow = x + (size_t)(rowBase + fr) * 256;
    const int og = fr >> 4;
    const int lrow = fr & 15;

    auto computeA = [&](int i) {
        float xv = xrow[i];
        float s1 = __sinf(xv);
        float c1 = __cosf(xv);
        float c2 = __builtin_fmaf(2.f * c1, c1, -1.f);
        float s2 = 2.f * s1 * c1;
        float m2 = 2.f * c2;
        float cx, cy, px, py;
        if (tg == 0) { cx = c1; cy = c2; px = c1;  py = 1.f; }
        else         { cx = s1; cy = s2; px = -s1; py = 0.f; }
        #pragma unroll
        for (int oct = 0; oct < 8; ++oct) {
            unsigned pk0, pk1, pk2, pk3;
            pk0 = pkbf16(cx, cy);
            { float nx = __builtin_fmaf(m2, cx, -px), ny = __builtin_fmaf(m2, cy, -py);
              px = cx; py = cy; cx = nx; cy = ny; }
            pk1 = pkbf16(cx, cy);
            { float nx = __builtin_fmaf(m2, cx, -px), ny = __builtin_fmaf(m2, cy, -py);
              px = cx; py = cy; cx = nx; cy = ny; }
            pk2 = pkbf16(cx, cy);
            { float nx = __builtin_fmaf(m2, cx, -px), ny = __builtin_fmaf(m2, cy, -py);
              px = cx; py = cy; cx = nx; cy = ny; }
            pk3 = pkbf16(cx, cy);
            { float nx = __builtin_fmaf(m2, cx, -px), ny = __builtin_fmaf(m2, cy, -py);
              px = cx; py = cy; cx = nx; cy = ny; }
            int k = tg * 64 + oct * 8;
            int s = k >> 5;
            int q = (k >> 3) & 3;
            uint4 v; v.x = pk0; v.y = pk1; v.z = pk2; v.w = pk3;
            Aimg[(s * 8 + og) * 64 + q * 16 + lrow] = v;
        }
    };

    auto stageB_ws = [&](int i) {
        const unsigned short* base = bws + ((size_t)(i * 2 + by) * 2048) * 8;
        #pragma unroll
        for (int cc = 0; cc < 8; ++cc) {
            int c = cc * 4 + w;                   // wave-uniform chunk id
            async_load16(base + (size_t)(c * 64 + l) * 8, (void*)(Bimg + c * 64));
        }
    };

    auto stageB_direct = [&](int i) {
        #pragma unroll
        for (int gg = 0; gg < 8; ++gg) {
            int gi  = gg * 256 + t;
            int sog = gi >> 6;
            int ll  = gi & 63;
            int s = sog >> 3, ogb = sog & 7;
            int o = ogb * 16 + (ll & 15);
            int k = s * 32 + (ll >> 4) * 8;
            int tt = k >> 6, g = k & 63;
            const float4* p = (const float4*)(fc +
                ((((size_t)tt * 256 + colBase + o) * 256 + i) * 64 + g));
            float4 a = p[0], b = p[1];
            uint4 v;
            v.x = pkbf16(a.x, a.y); v.y = pkbf16(a.z, a.w);
            v.z = pkbf16(b.x, b.y); v.w = pkbf16(b.z, b.w);
            Bimg[gi] = v;
        }
    };

    // preamble: stage iteration 0
    if (USE_WS) stageB_ws(iBase);
    computeA(iBase);
    if (!USE_WS) stageB_direct(iBase);

    #pragma unroll 1
    for (int ii = 0; ii < ICHUNK; ++ii) {
        __syncthreads();   // A writes visible; async B loads drained (vmcnt 0)

        // register-prefetch ALL fragments for this iteration
        short8 aF[4][4], bF[4][4];
        #pragma unroll
        for (int s = 0; s < 4; ++s) {
            #pragma unroll
            for (int rf = 0; rf < 4; ++rf)
                aF[s][rf] = __builtin_bit_cast(short8, Aimg[(s * 8 + wr * 4 + rf) * 64 + l]);
            #pragma unroll
            for (int cf = 0; cf < 4; ++cf)
                bF[s][cf] = __builtin_bit_cast(short8, Bimg[(s * 8 + wc * 4 + cf) * 64 + l]);
        }

        __syncthreads();   // all frags in regs; LDS free for next iteration

        if (ii + 1 < ICHUNK) {
            int ni = iBase + ii + 1;
            if (USE_WS) stageB_ws(ni);      // async, lands before next barrier
            computeA(ni);                    // VALU overlaps MFMA below
            if (!USE_WS) stageB_direct(ni);
        }

        #pragma unroll
        for (int s = 0; s < 4; ++s)
            #pragma unroll
            for (int rf = 0; rf < 4; ++rf)
                #pragma unroll
                for (int cf = 0; cf < 4; ++cf)
                    acc[rf][cf] = __builtin_amdgcn_mfma_f32_16x16x32_bf16(
                        aF[s][rf], bF[s][cf], acc[rf][cf], 0, 0, 0);
    }

    // epilogue: C/D layout col=l&15, row=(l>>4)*4+e ; splitK via atomics
    const int lr = (l >> 4) * 4;
    const int lc = l & 15;
    const int r0 = rowBase + wr * 64 + lr;
    const int c0 = colBase + wc * 64 + lc;
    #pragma unroll
    for (int rf = 0; rf < 4; ++rf)
        #pragma unroll
        for (int cf = 0; cf < 4; ++cf)
            #pragma unroll
            for (int e = 0; e < 4; ++e)
                atomicAdd(out + (size_t)(r0 + rf * 16 + e) * 256 + (c0 + cf * 16),
                          acc[rf][cf][e]);
}

extern "C" void kernel_launch(void* const* d_in, const int* in_sizes, int n_in,
                              void* d_out, int out_size, void* d_ws, size_t ws_size,
                              hipStream_t stream) {
    const float* x    = (const float*)d_in[0];
    const float* fc   = (const float*)d_in[1];
    const float* bias = (const float*)d_in[2];
    float* out = (float*)d_out;
    unsigned short* bws = (unsigned short*)d_ws;

    hipLaunchKernelGGL(init_out_kernel, dim3(1024), dim3(256), 0, stream, out, bias);

    const size_t wsNeed = (size_t)512 * 2048 * 16;   // 16.78 MB image-order coeffs
    if (ws_size >= wsNeed) {
        hipLaunchKernelGGL(convert_coeffs2, dim3(512), dim3(256), 0, stream, fc, bws);
        hipLaunchKernelGGL((fkan_gemm<true>), dim3(32, 2, SPLITK), dim3(256), 0, stream,
                           x, fc, bws, out);
    } else {
        hipLaunchKernelGGL((fkan_gemm<false>), dim3(32, 2, SPLITK), dim3(256), 0, stream,
                           x, fc, bws, out);
    }
}